// Round 9
// baseline (377.888 us; speedup 1.0000x reference)
//
#include <hip/hip_runtime.h>

// ---------------------------------------------------------------------------
// MultiHeadAttention_60000693125780 — round 14
//  r13 lesson: launch fusion gains are ~5us/kernel; absmax tripwire held.
//  r14 halves barrier+vmcnt(0)-drain instances in pv & conv_o via 8-wave
//  (512-thr) blocks at constant 8 waves/CU (the r13 scores_sm pattern):
//   - pv: 128q x 128t tile, BK=128, 64KB LDS, grid (4,2,32)=256 (was 512
//     blocks x 4 rounds). Vt-refetch per output halves.
//   - conv_o: 256px (full row) x 64co, BK=128, 80KB LDS, grid (32,8)=256.
//     Woh L2-refetch halves (302->151MB).
//  Same tap/kc/ks ascending K-order per output -> bit-identical: absmax
//  must stay exactly 0.046875. conv_qkv ~125us tripwire.
// Layouts: Qh,Kh [nn][dd][t] f16; Vt [nn][t=256 feat][k=512] f16;
//  Ph [nn][q][k'] f16; Sp padded NHWC f16 [4][10][258][512]
// Pitch-64 swizzle: row u>>3, slot (u&7)^(row&7); reader (ks*4+lq)^(row&7).
// Pitch-128 swizzle: row u>>4, slot (u&15)^(row&15); reader (ks*4+lq)^(row&15).
// 512-thr staging: call j stages 8KB; unit u=j*512+tid -> row u>>4,
//  slot (tid&15)^(row&15), dest = base + u*16B (linear; swizzle on src, G21).
// ---------------------------------------------------------------------------

typedef __attribute__((ext_vector_type(8))) short short8;
typedef __attribute__((ext_vector_type(8))) _Float16 half8;
typedef __attribute__((ext_vector_type(4))) float f32x4;
typedef __attribute__((ext_vector_type(4))) short short4v;

#define MFMA16F(a, b, c) __builtin_amdgcn_mfma_f32_16x16x32_f16((a), (b), (c), 0, 0, 0)

__device__ __forceinline__ void gl_lds16(const void* g, void* l) {
    __builtin_amdgcn_global_load_lds(
        (const __attribute__((address_space(1))) unsigned int*)g,
        (__attribute__((address_space(3))) unsigned int*)l, 16, 0, 0);
}
__device__ __forceinline__ unsigned short f2h(float f) {
    _Float16 h = (_Float16)f;                       // RNE
    return __builtin_bit_cast(unsigned short, h);
}

// ---- fused prep: [0,1536) inputs | [1536,3584) weights | [3584,5600) halo
__global__ __launch_bounds__(256) void k_prep_fused(
        const float* __restrict__ q, const float* __restrict__ k,
        const float* __restrict__ v,
        const float* __restrict__ Wq, const float* __restrict__ Wk,
        const float* __restrict__ Wv, const float* __restrict__ Wo,
        unsigned short* __restrict__ Wqh, unsigned short* __restrict__ Wkh,
        unsigned short* __restrict__ Wvh, unsigned short* __restrict__ Woh,
        unsigned short* __restrict__ Xqh, unsigned short* __restrict__ Xkh,
        unsigned short* __restrict__ Xvh) {
    __shared__ __align__(16) unsigned int U[8192];
    const int b = blockIdx.x;
    const int tid = threadIdx.x;
    if (b < 1536) {
        // ---- inputs: NCHW fp32 -> padded NHWC f16 (single) ----
        const int cig = b & 15, n = (b >> 4) & 31, z = b >> 9;
        const float* X = z == 0 ? q : z == 1 ? k : v;
        unsigned short* Xh = z == 0 ? Xqh : z == 1 ? Xkh : Xvh;
#pragma unroll
        for (int it = 0; it < 8; ++it) {
            int ci_l = it * 4 + (tid >> 6);
            int pos = (tid & 63) * 4;
            const float4 rd =
                *(const float4*)&X[(size_t)(n * 512 + cig * 32 + ci_l) * 256 + pos];
            uint4 u;
            u.x = f2h(rd.x);
            u.y = f2h(rd.y);
            u.z = f2h(rd.z);
            u.w = f2h(rd.w);
            *(uint4*)&U[ci_l * 256 + pos] = u;
        }
        __syncthreads();
#pragma unroll
        for (int it = 0; it < 4; ++it) {
            int pos = it * 64 + (tid >> 2);
            int ci8 = (tid & 3) * 8;
            short8 h8;
#pragma unroll
            for (int j = 0; j < 8; ++j)
                h8[j] = (short)(U[(ci8 + j) * 256 + pos] & 0xffffu);
            int yy = (pos >> 3) + 1, xx = (pos & 7) + 1;
            size_t o = (size_t)((n * 34 + yy) * 10 + xx) * 512 + cig * 32 + ci8;
            *(short8*)&Xh[o] = h8;
        }
    } else if (b < 3584) {
        // ---- weights: [co][ci][tap] fp32 -> [co][tap][ci] f16 ----
        const int bl = b - 1536;
        const int co = bl & 511, z = bl >> 9;
        const float* W = z == 0 ? Wq : z == 1 ? Wk : z == 2 ? Wv : Wo;
        unsigned short* Wh = z == 0 ? Wqh : z == 1 ? Wkh : z == 2 ? Wvh : Woh;
        const float* Wc = W + co * 4608;
#pragma unroll
        for (int it = 0; it < 9; ++it) {
            int p = it * 256 + tid;
            float2 rd = *(const float2*)&Wc[p * 2];
            int e0 = p * 2;
            int ci0 = e0 / 9, t0 = e0 - ci0 * 9;
            U[t0 * 512 + ci0] = f2h(rd.x);
            int e1 = e0 + 1;
            int ci1 = e1 / 9, t1 = e1 - ci1 * 9;
            U[t1 * 512 + ci1] = f2h(rd.y);
        }
        __syncthreads();
        unsigned short* Whc = Wh + co * 4608;
#pragma unroll
        for (int it = 0; it < 18; ++it) {
            int j = it * 256 + tid;
            Whc[j] = (unsigned short)U[j];
        }
    } else {
        // ---- halo zeroing: 84 halo cells per (array, n), 3 arrays ----
        const int w = tid >> 6, l = tid & 63;
        int job = (b - 3584) * 4 + w;        // 8064 jobs = 3 arrays * 32 n * 84
        int a = job / 2688;
        int r = job - a * 2688;
        int n = r / 84;
        int ii = r - n * 84;
        unsigned short* arr = a == 0 ? Xqh : a == 1 ? Xkh : Xvh;
        int cell;
        if (ii < 11)      cell = ii;
        else if (ii < 73) { int j = ii - 11; cell = 19 + (j >> 1) * 10 + (j & 1); }
        else              cell = 329 + (ii - 73);
        short8 z8 = {0, 0, 0, 0, 0, 0, 0, 0};
        *(short8*)&arr[(size_t)(n * 340 + cell) * 512 + l * 8] = z8;
    }
}

// ---- merged QKV conv, BK=64, ONE uniform single-pass f16 loop (r12) ----
__global__ __launch_bounds__(256) void k_conv_qkv_all(
        const unsigned short* __restrict__ Xqh, const unsigned short* __restrict__ Xkh,
        const unsigned short* __restrict__ Xvh,
        const unsigned short* __restrict__ Wqh_, const unsigned short* __restrict__ Wkh_,
        const unsigned short* __restrict__ Wvh_,
        const float* __restrict__ bq, const float* __restrict__ bk,
        const float* __restrict__ bv,
        unsigned short* __restrict__ Qh, unsigned short* __restrict__ Kh,
        unsigned short* __restrict__ Vt) {
    __shared__ __align__(16) short Ah[8192], Bh[8192];   // 32KB
    const int z = blockIdx.z;
    const unsigned short* Xh = z == 0 ? Xqh : z == 1 ? Xkh : Xvh;
    const unsigned short* Wh = z == 0 ? Wqh_ : z == 1 ? Wkh_ : Wvh_;
    const float* bias = z == 0 ? bq : z == 1 ? bk : bv;

    const int tid = threadIdx.x;
    const int w = tid >> 6, l = tid & 63;
    const int n   = blockIdx.x >> 1;
    const int p0  = (blockIdx.x & 1) * 128;
    const int co0 = blockIdx.y * 128;
    const int lm = l & 15, lq = l >> 4;
    const int r8 = l >> 3, c8 = (l & 7) ^ (l >> 3);      // pitch-64 stage map

    int arow[4], brow[4];
#pragma unroll
    for (int j = 0; j < 4; ++j) {
        int rt = w * 32 + j * 8 + r8;
        int px = p0 + rt;
        int y = px >> 3, x = px & 7;
        arow[j] = ((n * 34 + y + 1) * 10 + (x + 1)) * 512 + c8 * 8;
        brow[j] = (co0 + rt) * 4608 + c8 * 8;
    }
    const int ldsW = w * 4096;       // bytes: wave's 32 rows x 128B

    int aoff[4][2], boff[4][2];
#pragma unroll
    for (int mi = 0; mi < 4; ++mi) {
        int row = (w & 1) * 64 + mi * 16 + lm;
#pragma unroll
        for (int ks = 0; ks < 2; ++ks)
            aoff[mi][ks] = row * 64 + ((((ks << 2) | lq) ^ (row & 7)) * 8);
    }
#pragma unroll
    for (int ni = 0; ni < 4; ++ni) {
        int row = (w >> 1) * 64 + ni * 16 + lm;
#pragma unroll
        for (int ks = 0; ks < 2; ++ks)
            boff[ni][ks] = row * 64 + ((((ks << 2) | lq) ^ (row & 7)) * 8);
    }

    f32x4 acc[4][4];
#pragma unroll
    for (int ni = 0; ni < 4; ++ni) {
        float b = bias[co0 + (w >> 1) * 64 + ni * 16 + lm];
#pragma unroll
        for (int mi = 0; mi < 4; ++mi) acc[mi][ni] = (f32x4){b, b, b, b};
    }

    for (int tap = 0; tap < 9; ++tap) {
        const int tapoff = ((tap / 3 - 1) * 10 + (tap % 3 - 1)) * 512;
        const int wb = tap * 512;
        for (int ci0 = 0; ci0 < 512; ci0 += 64) {
#pragma unroll
            for (int j = 0; j < 4; ++j)
                gl_lds16(Xh + arow[j] + tapoff + ci0, (char*)Ah + ldsW + j * 1024);
#pragma unroll
            for (int j = 0; j < 4; ++j)
                gl_lds16(Wh + brow[j] + wb + ci0, (char*)Bh + ldsW + j * 1024);
            __syncthreads();
            __builtin_amdgcn_s_setprio(1);
#pragma unroll
            for (int ks = 0; ks < 2; ++ks) {
                half8 ah[4], bh[4];
#pragma unroll
                for (int mi = 0; mi < 4; ++mi)
                    ah[mi] = *(const half8*)&Ah[aoff[mi][ks]];
#pragma unroll
                for (int ni = 0; ni < 4; ++ni)
                    bh[ni] = *(const half8*)&Bh[boff[ni][ks]];
#pragma unroll
                for (int mi = 0; mi < 4; ++mi)
#pragma unroll
                    for (int ni = 0; ni < 4; ++ni)
                        acc[mi][ni] = MFMA16F(ah[mi], bh[ni], acc[mi][ni]);
            }
            __builtin_amdgcn_s_setprio(0);
            __syncthreads();
        }
    }

    const int hh = n >> 2, nl = n & 3;
    const int pxbase = p0 + (w & 1) * 64 + lq * 4;
    const int x0q = pxbase & 7;
#pragma unroll
    for (int mi = 0; mi < 4; ++mi) {
        int px = pxbase + mi * 16;
        int y = px >> 3;
#pragma unroll
        for (int ni = 0; ni < 4; ++ni) {
            int co = co0 + (w >> 1) * 64 + ni * 16 + lm;
            int nn = nl * 8 + (co >> 6);
            int dd = (co & 63) * 8 + (y >> 2);
            int t0 = hh * 32 + (y & 3) * 8 + x0q;
            if (z < 2) {                       // Q,K: single f16
                unsigned short* O = (z == 0) ? Qh : Kh;
                short4v hv;
#pragma unroll
                for (int r = 0; r < 4; ++r) hv[r] = (short)f2h(acc[mi][ni][r]);
                *(short4v*)&O[(nn * 512 + dd) * 256 + t0] = hv;
            } else {                           // V: f16 transposed
#pragma unroll
                for (int r = 0; r < 4; ++r)
                    Vt[(nn * 256 + t0 + r) * 512 + dd] = f2h(acc[mi][ni][r]);
            }
        }
    }
}

// ---- FUSED scores+softmax (r13, staging expr cleaned): 64q x 512k/block ----
__global__ __launch_bounds__(512) void k_scores_sm(
        const unsigned short* __restrict__ Qh, const unsigned short* __restrict__ Kh,
        float* __restrict__ Sc, unsigned short* __restrict__ Ph,
        uint4* __restrict__ Spz) {
    __shared__ __align__(16) short Ah[4096], Bh[32768];  // 8KB + 64KB
    __shared__ float Mw[8][64], Sw[8][64];               // 4KB
    const int tid = threadIdx.x;
    const int nn = blockIdx.y, q0 = blockIdx.x * 64;

    // zero Sp (660480 uint4 over 131072 threads)
    {
        unsigned g = (blockIdx.y * 8u + blockIdx.x) * 512u + tid;
#pragma unroll
        for (int i = 0; i < 6; ++i) {
            unsigned zi = g + (unsigned)i * 131072u;
            if (zi < 660480u) Spz[zi] = (uint4){0u, 0u, 0u, 0u};
        }
    }

    const int w = tid >> 6, l = tid & 63;
    const int wq = w & 1, wk = w >> 1;
    const int lm = l & 15, lq = l >> 4;

    // staging addresses (pitch-64 swizzle on global src; LDS dest linear)
    const int ar = tid >> 3, ac = (tid & 7) ^ ((tid >> 3) & 7);   // A: 64 rows
    const int arow = (nn * 512 + q0 + ar) * 256 + ac * 8;
    int brow[8];
#pragma unroll
    for (int it = 0; it < 8; ++it) {
        int u = it * 512 + tid;
        int row = u >> 3, slot = u & 7;
        brow[it] = (nn * 512 + row) * 256 + ((slot ^ (row & 7)) * 8);
    }

    int aoff[2][2], boff[8][2];
#pragma unroll
    for (int mi = 0; mi < 2; ++mi) {
        int row = wq * 32 + mi * 16 + lm;
#pragma unroll
        for (int ks = 0; ks < 2; ++ks)
            aoff[mi][ks] = row * 64 + ((((ks << 2) | lq) ^ (row & 7)) * 8);
    }
#pragma unroll
    for (int ni = 0; ni < 8; ++ni) {
        int row = wk * 128 + ni * 16 + lm;
#pragma unroll
        for (int ks = 0; ks < 2; ++ks)
            boff[ni][ks] = row * 64 + ((((ks << 2) | lq) ^ (row & 7)) * 8);
    }

    f32x4 acc[2][8];
#pragma unroll
    for (int mi = 0; mi < 2; ++mi)
#pragma unroll
        for (int ni = 0; ni < 8; ++ni) acc[mi][ni] = (f32x4){0.f, 0.f, 0.f, 0.f};

    for (int tc = 0; tc < 256; tc += 64) {
        gl_lds16(Qh + arow + tc, (char*)Ah + tid * 16);
#pragma unroll
        for (int it = 0; it < 8; ++it)
            gl_lds16(Kh + brow[it] + tc, (char*)Bh + (it * 512 + tid) * 16);
        __syncthreads();
        __builtin_amdgcn_s_setprio(1);
#pragma unroll
        for (int ks = 0; ks < 2; ++ks) {
            half8 ah[2], bh[8];
#pragma unroll
            for (int mi = 0; mi < 2; ++mi) ah[mi] = *(const half8*)&Ah[aoff[mi][ks]];
#pragma unroll
            for (int ni = 0; ni < 8; ++ni) bh[ni] = *(const half8*)&Bh[boff[ni][ks]];
#pragma unroll
            for (int mi = 0; mi < 2; ++mi)
#pragma unroll
                for (int ni = 0; ni < 8; ++ni)
                    acc[mi][ni] = MFMA16F(ah[mi], bh[ni], acc[mi][ni]);
        }
        __builtin_amdgcn_s_setprio(0);
        __syncthreads();
    }

    // ---- in-register softmax over k ----
    float M[2][4];
#pragma unroll
    for (int mi = 0; mi < 2; ++mi)
#pragma unroll
        for (int r = 0; r < 4; ++r) {
            float m = acc[mi][0][r];
#pragma unroll
            for (int ni = 1; ni < 8; ++ni) m = fmaxf(m, acc[mi][ni][r]);
#pragma unroll
            for (int off = 1; off < 16; off <<= 1) m = fmaxf(m, __shfl_xor(m, off));
            M[mi][r] = m;
            if (lm == 0) Mw[w][wq * 32 + mi * 16 + lq * 4 + r] = m;
        }
    __syncthreads();
#pragma unroll
    for (int mi = 0; mi < 2; ++mi)
#pragma unroll
        for (int r = 0; r < 4; ++r) {
            int q_l = wq * 32 + mi * 16 + lq * 4 + r;
            float m = fmaxf(fmaxf(Mw[wq][q_l], Mw[wq + 2][q_l]),
                            fmaxf(Mw[wq + 4][q_l], Mw[wq + 6][q_l]));
            M[mi][r] = m;
        }
#pragma unroll
    for (int mi = 0; mi < 2; ++mi)
#pragma unroll
        for (int r = 0; r < 4; ++r) {
            float m = M[mi][r];
            float s = 0.f;
#pragma unroll
            for (int ni = 0; ni < 8; ++ni) {
                float e = __expf(acc[mi][ni][r] - m);
                acc[mi][ni][r] = e;
                s += e;
            }
#pragma unroll
            for (int off = 1; off < 16; off <<= 1) s += __shfl_xor(s, off);
            if (lm == 0) Sw[w][wq * 32 + mi * 16 + lq * 4 + r] = s;
        }
    __syncthreads();
    float* C = Sc + nn * 262144;
    unsigned short* P = Ph + nn * 262144;
#pragma unroll
    for (int mi = 0; mi < 2; ++mi)
#pragma unroll
        for (int r = 0; r < 4; ++r) {
            int q_l = wq * 32 + mi * 16 + lq * 4 + r;
            float s = ((Sw[wq][q_l] + Sw[wq + 2][q_l]) +
                       (Sw[wq + 4][q_l] + Sw[wq + 6][q_l]));
            float inv = 1.0f / s;
            int rowbase = (q0 + q_l) * 512 + wk * 128 + lm;
#pragma unroll
            for (int ni = 0; ni < 8; ++ni) {
                float p = acc[mi][ni][r] * inv;
                C[rowbase + ni * 16] = p;
                P[rowbase + ni * 16] = f2h(p);
            }
        }
}

// ---- PV: 128q x 128t tile, 8 waves (2x4), BK=128, grid (4,2,32)=256 ----
__global__ __launch_bounds__(512) void k_pv_mfma(
        const unsigned short* __restrict__ Ph, const unsigned short* __restrict__ Vt,
        unsigned short* __restrict__ Sp) {
    __shared__ __align__(16) short Ah[16384], Bh[16384]; // [128][128] x2 = 64KB
    const int tid = threadIdx.x;
    const int w = tid >> 6, l = tid & 63;
    const int q0 = blockIdx.x * 128, t0 = blockIdx.y * 128, nn = blockIdx.z;
    const int wq = w & 1, wt = w >> 1;
    const int lm = l & 15, lq = l >> 4;
    const int sr = tid >> 4, sc = tid & 15;              // 512-thr stage map

    int arow[4], brow[4];
#pragma unroll
    for (int j = 0; j < 4; ++j) {
        int rt = j * 32 + sr;                            // 0..127
        int slot = sc ^ (rt & 15);
        arow[j] = (nn * 512 + q0 + rt) * 512 + slot * 8;
        brow[j] = (nn * 256 + t0 + rt) * 512 + slot * 8;
    }

    int aoff[4][4], boff[2][4];
#pragma unroll
    for (int mi = 0; mi < 4; ++mi) {
        int row = wq * 64 + mi * 16 + lm;
#pragma unroll
        for (int ks = 0; ks < 4; ++ks)
            aoff[mi][ks] = row * 128 + ((((ks << 2) | lq) ^ (row & 15)) * 8);
    }
#pragma unroll
    for (int ni = 0; ni < 2; ++ni) {
        int row = wt * 32 + ni * 16 + lm;
#pragma unroll
        for (int ks = 0; ks < 4; ++ks)
            boff[ni][ks] = row * 128 + ((((ks << 2) | lq) ^ (row & 15)) * 8);
    }

    f32x4 acc[4][2];
#pragma unroll
    for (int mi = 0; mi < 4; ++mi)
#pragma unroll
        for (int ni = 0; ni < 2; ++ni) acc[mi][ni] = (f32x4){0.f, 0.f, 0.f, 0.f};

    for (int kc = 0; kc < 512; kc += 128) {
#pragma unroll
        for (int j = 0; j < 4; ++j)
            gl_lds16(Ph + arow[j] + kc, (char*)Ah + (j * 512 + tid) * 16);
#pragma unroll
        for (int j = 0; j < 4; ++j)
            gl_lds16(Vt + brow[j] + kc, (char*)Bh + (j * 512 + tid) * 16);
        __syncthreads();
        __builtin_amdgcn_s_setprio(1);
#pragma unroll
        for (int ks = 0; ks < 4; ++ks) {
            half8 a[4], b[2];
#pragma unroll
            for (int mi = 0; mi < 4; ++mi) a[mi] = *(const half8*)&Ah[aoff[mi][ks]];
#pragma unroll
            for (int ni = 0; ni < 2; ++ni) b[ni] = *(const half8*)&Bh[boff[ni][ks]];
#pragma unroll
            for (int mi = 0; mi < 4; ++mi)
#pragma unroll
                for (int ni = 0; ni < 2; ++ni)
                    acc[mi][ni] = MFMA16F(a[mi], b[ni], acc[mi][ni]);
        }
        __builtin_amdgcn_s_setprio(0);
        __syncthreads();
    }

    // scatter into Sp[b2][yy][xx][d2]:  b2=nn>>3, s2=nn&7,
    //   ww=(qp>>4)*8+((qp>>1)&7), d2=(qp&1)*256+(t&31)*8+(t>>5)
    const int b2 = nn >> 3, s2 = nn & 7;
#pragma unroll
    for (int mi = 0; mi < 4; ++mi) {
        int qb = q0 + wq * 64 + lq * 4 + mi * 16;
#pragma unroll
        for (int ni = 0; ni < 2; ++ni) {
            int tc = t0 + wt * 32 + ni * 16 + lm;
            int d2base = (tc & 31) * 8 + (tc >> 5);
#pragma unroll
            for (int r = 0; r < 4; ++r) {
                int qp = qb + r;
                int ww = (qp >> 4) * 8 + ((qp >> 1) & 7);
                int d2 = (qp & 1) * 256 + d2base;
                Sp[((b2 * 10 + s2 + 1) * 258 + ww + 1) * 512 + d2] =
                    f2h(acc[mi][ni][r]);
            }
        }
    }
}

// ---- output conv: 256px (full row) x 64co, 8 waves (4x2), BK=128 ----
__global__ __launch_bounds__(512) void k_conv_o_mfma(
        const unsigned short* __restrict__ Sp, const unsigned short* __restrict__ Wh,
        const float* __restrict__ bias, float* __restrict__ Y) {
    __shared__ __align__(16) short Ah[32768], Bh[8192];  // [256][128]+[64][128]=80KB
    const int tid = threadIdx.x;
    const int w = tid >> 6, l = tid & 63;
    const int n   = blockIdx.x >> 3;
    const int yy  = blockIdx.x & 7;
    const int co0 = blockIdx.y * 64;
    const int wp = w & 3, wc = w >> 2;
    const int lm = l & 15, lq = l >> 4;
    const int sr = tid >> 4, sc = tid & 15;              // 512-thr stage map

    int arow[8], brow[2];
#pragma unroll
    for (int j = 0; j < 8; ++j) {
        int rt = j * 32 + sr;                            // 0..255
        int slot = sc ^ (rt & 15);
        arow[j] = ((n * 10 + yy + 1) * 258 + (rt + 1)) * 512 + slot * 8;
    }
#pragma unroll
    for (int j = 0; j < 2; ++j) {
        int rt = j * 32 + sr;                            // 0..63
        int slot = sc ^ (rt & 15);
        brow[j] = (co0 + rt) * 4608 + slot * 8;
    }

    int aoff[4][4], boff[2][4];
#pragma unroll
    for (int mi = 0; mi < 4; ++mi) {
        int row = wp * 64 + mi * 16 + lm;
#pragma unroll
        for (int ks = 0; ks < 4; ++ks)
            aoff[mi][ks] = row * 128 + ((((ks << 2) | lq) ^ (row & 15)) * 8);
    }
#pragma unroll
    for (int ni = 0; ni < 2; ++ni) {
        int row = wc * 32 + ni * 16 + lm;
#pragma unroll
        for (int ks = 0; ks < 4; ++ks)
            boff[ni][ks] = row * 128 + ((((ks << 2) | lq) ^ (row & 15)) * 8);
    }

    f32x4 acc[4][2];
#pragma unroll
    for (int ni = 0; ni < 2; ++ni) {
        float b = bias[co0 + wc * 32 + ni * 16 + lm];
#pragma unroll
        for (int mi = 0; mi < 4; ++mi) acc[mi][ni] = (f32x4){b, b, b, b};
    }

    for (int tap = 0; tap < 9; ++tap) {
        const int tapoff = ((tap / 3 - 1) * 258 + (tap % 3 - 1)) * 512;
        const int wb = tap * 512;
        for (int ci0 = 0; ci0 < 512; ci0 += 128) {
#pragma unroll
            for (int j = 0; j < 8; ++j)
                gl_lds16(Sp + arow[j] + tapoff + ci0,
                         (char*)Ah + (j * 512 + tid) * 16);
#pragma unroll
            for (int j = 0; j < 2; ++j)
                gl_lds16(Wh + brow[j] + wb + ci0,
                         (char*)Bh + (j * 512 + tid) * 16);
            __syncthreads();
            __builtin_amdgcn_s_setprio(1);
#pragma unroll
            for (int ks = 0; ks < 4; ++ks) {
                half8 a[4], b[2];
#pragma unroll
                for (int mi = 0; mi < 4; ++mi)
                    a[mi] = *(const half8*)&Ah[aoff[mi][ks]];
#pragma unroll
                for (int ni = 0; ni < 2; ++ni)
                    b[ni] = *(const half8*)&Bh[boff[ni][ks]];
#pragma unroll
                for (int mi = 0; mi < 4; ++mi)
#pragma unroll
                    for (int ni = 0; ni < 2; ++ni)
                        acc[mi][ni] = MFMA16F(a[mi], b[ni], acc[mi][ni]);
            }
            __builtin_amdgcn_s_setprio(0);
            __syncthreads();
        }
    }

#pragma unroll
    for (int mi = 0; mi < 4; ++mi) {
        int px = wp * 64 + lq * 4 + mi * 16;
#pragma unroll
        for (int ni = 0; ni < 2; ++ni) {
            int co = co0 + wc * 32 + ni * 16 + lm;
            *(f32x4*)&Y[n * 1048576 + co * 2048 + yy * 256 + px] = acc[mi][ni];
        }
    }
}

// ---------------------------------------------------------------------------
extern "C" void kernel_launch(void* const* d_in, const int* in_sizes, int n_in,
                              void* d_out, int out_size, void* d_ws, size_t ws_size,
                              hipStream_t stream) {
    const float* q  = (const float*)d_in[0];
    const float* k  = (const float*)d_in[1];
    const float* v  = (const float*)d_in[2];
    const float* Wq = (const float*)d_in[3];
    const float* bq = (const float*)d_in[4];
    const float* Wk = (const float*)d_in[5];
    const float* bk = (const float*)d_in[6];
    const float* Wv = (const float*)d_in[7];
    const float* bv = (const float*)d_in[8];
    const float* Wo = (const float*)d_in[9];
    const float* bo = (const float*)d_in[10];

    // ---- workspace layout (shorts) ----
    unsigned short* W0  = (unsigned short*)d_ws;
    unsigned short* Wqh = W0;                   // 2359296
    unsigned short* Wkh = W0 + 2359296;         // 2359296
    unsigned short* Wvh = W0 + 4718592;         // 2359296
    unsigned short* Xvh = W0 + 7077888;         // 5570560 (ends 12648448)
    unsigned short* Sp  = W0 + 12648448;        // 5283840 (no overlap with Ph@0,
                                                //  Woh@18219008, Qh/Kh/Vt)
    unsigned short* Woh = W0 + 18219008;        // 2359296 (alive till conv_o)
    unsigned short* Qh  = W0 + 20578304;        // 4194304
    unsigned short* Kh  = W0 + 28966912;        // 4194304
    unsigned short* Vt  = W0 + 33161216;        // 4194304 (alive till pv)
    // reuses: Ph @0 (8388608, over Wqh/Wkh/Wvh/Xvh-head — dead after conv)
    unsigned short* Ph = W0;                    // 8388608 shorts

    // ---- d_out scratch before final writes ----
    float* y_out = (float*)d_out;               // 4194304 floats (written last)
    float* attn  = y_out + 4194304;             // 8388608 floats (by scores_sm)
    unsigned short* Xqh = (unsigned short*)d_out;
    unsigned short* Xkh = (unsigned short*)attn;

    k_prep_fused<<<5600, 256, 0, stream>>>(q, k, v, Wq, Wk, Wv, Wo,
                                           Wqh, Wkh, Wvh, Woh,
                                           Xqh, Xkh, Xvh);
    k_conv_qkv_all<<<dim3(64, 4, 3), 256, 0, stream>>>(
        Xqh, Xkh, Xvh, Wqh, Wkh, Wvh,
        bq, bk, bv, Qh, Kh, Vt);
    k_scores_sm<<<dim3(8, 32), 512, 0, stream>>>(Qh, Kh, attn, Ph, (uint4*)Sp);
    k_pv_mfma<<<dim3(4, 2, 32), 512, 0, stream>>>(Ph, Vt, Sp);
    k_conv_o_mfma<<<dim3(32, 8), 512, 0, stream>>>(Sp, Woh, bo, y_out);
}

// Round 10
// 356.966 us; speedup vs baseline: 1.0586x; 1.0586x over previous
//
#include <hip/hip_runtime.h>

// ---------------------------------------------------------------------------
// MultiHeadAttention_60000693125780 — round 15 (revert of r14's pv/conv_o)
//  r14 lesson (CONFIRMED design rule): 8-wave 512-thr blocks at 1 block/CU
//  put all waves in ONE barrier domain -> no co-resident block to hide the
//  vmcnt(0)+barrier drain (m114 overlap lost) -> +16us despite halved drain
//  count. Every MFMA kernel here needs >=2 independent blocks/CU (conv_qkv
//  has 3; scores_sm tolerates 1/CU only because it has just 4 drain rounds).
//  pv & conv_o restored to r13 256-thr 2-blocks/CU forms.
//  State: conv_qkv at structural cap (~125us, 59us f16-MFMA floor + drains,
//  all schedule levers tested); fused scores_sm holds absmax tripwire.
//  Predicted: total 360-365, conv ~125-128, absmax exactly 0.046875.
// Layouts: Qh,Kh [nn][dd][t] f16; Vt [nn][t][dd] f16; Ph [nn][q][k'] f16;
//          Sp padded NHWC f16 [4][10][258][512]
// Pitch-64 swizzle: row u>>3, slot (u&7)^(row&7); reader (ks*4+lq)^(row&7).
// Pitch-128 swizzle: row u>>4, slot (u&15)^(row&15); reader (ks*4+lq)^(row&15).
// ---------------------------------------------------------------------------

typedef __attribute__((ext_vector_type(8))) short short8;
typedef __attribute__((ext_vector_type(8))) _Float16 half8;
typedef __attribute__((ext_vector_type(4))) float f32x4;
typedef __attribute__((ext_vector_type(4))) short short4v;

#define MFMA16F(a, b, c) __builtin_amdgcn_mfma_f32_16x16x32_f16((a), (b), (c), 0, 0, 0)

__device__ __forceinline__ void gl_lds16(const void* g, void* l) {
    __builtin_amdgcn_global_load_lds(
        (const __attribute__((address_space(1))) unsigned int*)g,
        (__attribute__((address_space(3))) unsigned int*)l, 16, 0, 0);
}
__device__ __forceinline__ unsigned short f2h(float f) {
    _Float16 h = (_Float16)f;                       // RNE
    return __builtin_bit_cast(unsigned short, h);
}

// ---- fused prep: [0,1536) inputs | [1536,3584) weights | [3584,5600) halo
__global__ __launch_bounds__(256) void k_prep_fused(
        const float* __restrict__ q, const float* __restrict__ k,
        const float* __restrict__ v,
        const float* __restrict__ Wq, const float* __restrict__ Wk,
        const float* __restrict__ Wv, const float* __restrict__ Wo,
        unsigned short* __restrict__ Wqh, unsigned short* __restrict__ Wkh,
        unsigned short* __restrict__ Wvh, unsigned short* __restrict__ Woh,
        unsigned short* __restrict__ Xqh, unsigned short* __restrict__ Xkh,
        unsigned short* __restrict__ Xvh) {
    __shared__ __align__(16) unsigned int U[8192];
    const int b = blockIdx.x;
    const int tid = threadIdx.x;
    if (b < 1536) {
        // ---- inputs: NCHW fp32 -> padded NHWC f16 (single) ----
        const int cig = b & 15, n = (b >> 4) & 31, z = b >> 9;
        const float* X = z == 0 ? q : z == 1 ? k : v;
        unsigned short* Xh = z == 0 ? Xqh : z == 1 ? Xkh : Xvh;
#pragma unroll
        for (int it = 0; it < 8; ++it) {
            int ci_l = it * 4 + (tid >> 6);
            int pos = (tid & 63) * 4;
            const float4 rd =
                *(const float4*)&X[(size_t)(n * 512 + cig * 32 + ci_l) * 256 + pos];
            uint4 u;
            u.x = f2h(rd.x);
            u.y = f2h(rd.y);
            u.z = f2h(rd.z);
            u.w = f2h(rd.w);
            *(uint4*)&U[ci_l * 256 + pos] = u;
        }
        __syncthreads();
#pragma unroll
        for (int it = 0; it < 4; ++it) {
            int pos = it * 64 + (tid >> 2);
            int ci8 = (tid & 3) * 8;
            short8 h8;
#pragma unroll
            for (int j = 0; j < 8; ++j)
                h8[j] = (short)(U[(ci8 + j) * 256 + pos] & 0xffffu);
            int yy = (pos >> 3) + 1, xx = (pos & 7) + 1;
            size_t o = (size_t)((n * 34 + yy) * 10 + xx) * 512 + cig * 32 + ci8;
            *(short8*)&Xh[o] = h8;
        }
    } else if (b < 3584) {
        // ---- weights: [co][ci][tap] fp32 -> [co][tap][ci] f16 ----
        const int bl = b - 1536;
        const int co = bl & 511, z = bl >> 9;
        const float* W = z == 0 ? Wq : z == 1 ? Wk : z == 2 ? Wv : Wo;
        unsigned short* Wh = z == 0 ? Wqh : z == 1 ? Wkh : z == 2 ? Wvh : Woh;
        const float* Wc = W + co * 4608;
#pragma unroll
        for (int it = 0; it < 9; ++it) {
            int p = it * 256 + tid;
            float2 rd = *(const float2*)&Wc[p * 2];
            int e0 = p * 2;
            int ci0 = e0 / 9, t0 = e0 - ci0 * 9;
            U[t0 * 512 + ci0] = f2h(rd.x);
            int e1 = e0 + 1;
            int ci1 = e1 / 9, t1 = e1 - ci1 * 9;
            U[t1 * 512 + ci1] = f2h(rd.y);
        }
        __syncthreads();
        unsigned short* Whc = Wh + co * 4608;
#pragma unroll
        for (int it = 0; it < 18; ++it) {
            int j = it * 256 + tid;
            Whc[j] = (unsigned short)U[j];
        }
    } else {
        // ---- halo zeroing: 84 halo cells per (array, n), 3 arrays ----
        const int w = tid >> 6, l = tid & 63;
        int job = (b - 3584) * 4 + w;        // 8064 jobs = 3 arrays * 32 n * 84
        int a = job / 2688;
        int r = job - a * 2688;
        int n = r / 84;
        int ii = r - n * 84;
        unsigned short* arr = a == 0 ? Xqh : a == 1 ? Xkh : Xvh;
        int cell;
        if (ii < 11)      cell = ii;
        else if (ii < 73) { int j = ii - 11; cell = 19 + (j >> 1) * 10 + (j & 1); }
        else              cell = 329 + (ii - 73);
        short8 z8 = {0, 0, 0, 0, 0, 0, 0, 0};
        *(short8*)&arr[(size_t)(n * 340 + cell) * 512 + l * 8] = z8;
    }
}

// ---- merged QKV conv, BK=64, ONE uniform single-pass f16 loop (r12) ----
__global__ __launch_bounds__(256) void k_conv_qkv_all(
        const unsigned short* __restrict__ Xqh, const unsigned short* __restrict__ Xkh,
        const unsigned short* __restrict__ Xvh,
        const unsigned short* __restrict__ Wqh_, const unsigned short* __restrict__ Wkh_,
        const unsigned short* __restrict__ Wvh_,
        const float* __restrict__ bq, const float* __restrict__ bk,
        const float* __restrict__ bv,
        unsigned short* __restrict__ Qh, unsigned short* __restrict__ Kh,
        unsigned short* __restrict__ Vt) {
    __shared__ __align__(16) short Ah[8192], Bh[8192];   // 32KB
    const int z = blockIdx.z;
    const unsigned short* Xh = z == 0 ? Xqh : z == 1 ? Xkh : Xvh;
    const unsigned short* Wh = z == 0 ? Wqh_ : z == 1 ? Wkh_ : Wvh_;
    const float* bias = z == 0 ? bq : z == 1 ? bk : bv;

    const int tid = threadIdx.x;
    const int w = tid >> 6, l = tid & 63;
    const int n   = blockIdx.x >> 1;
    const int p0  = (blockIdx.x & 1) * 128;
    const int co0 = blockIdx.y * 128;
    const int lm = l & 15, lq = l >> 4;
    const int r8 = l >> 3, c8 = (l & 7) ^ (l >> 3);      // pitch-64 stage map

    int arow[4], brow[4];
#pragma unroll
    for (int j = 0; j < 4; ++j) {
        int rt = w * 32 + j * 8 + r8;
        int px = p0 + rt;
        int y = px >> 3, x = px & 7;
        arow[j] = ((n * 34 + y + 1) * 10 + (x + 1)) * 512 + c8 * 8;
        brow[j] = (co0 + rt) * 4608 + c8 * 8;
    }
    const int ldsW = w * 4096;       // bytes: wave's 32 rows x 128B

    int aoff[4][2], boff[4][2];
#pragma unroll
    for (int mi = 0; mi < 4; ++mi) {
        int row = (w & 1) * 64 + mi * 16 + lm;
#pragma unroll
        for (int ks = 0; ks < 2; ++ks)
            aoff[mi][ks] = row * 64 + ((((ks << 2) | lq) ^ (row & 7)) * 8);
    }
#pragma unroll
    for (int ni = 0; ni < 4; ++ni) {
        int row = (w >> 1) * 64 + ni * 16 + lm;
#pragma unroll
        for (int ks = 0; ks < 2; ++ks)
            boff[ni][ks] = row * 64 + ((((ks << 2) | lq) ^ (row & 7)) * 8);
    }

    f32x4 acc[4][4];
#pragma unroll
    for (int ni = 0; ni < 4; ++ni) {
        float b = bias[co0 + (w >> 1) * 64 + ni * 16 + lm];
#pragma unroll
        for (int mi = 0; mi < 4; ++mi) acc[mi][ni] = (f32x4){b, b, b, b};
    }

    for (int tap = 0; tap < 9; ++tap) {
        const int tapoff = ((tap / 3 - 1) * 10 + (tap % 3 - 1)) * 512;
        const int wb = tap * 512;
        for (int ci0 = 0; ci0 < 512; ci0 += 64) {
#pragma unroll
            for (int j = 0; j < 4; ++j)
                gl_lds16(Xh + arow[j] + tapoff + ci0, (char*)Ah + ldsW + j * 1024);
#pragma unroll
            for (int j = 0; j < 4; ++j)
                gl_lds16(Wh + brow[j] + wb + ci0, (char*)Bh + ldsW + j * 1024);
            __syncthreads();
            __builtin_amdgcn_s_setprio(1);
#pragma unroll
            for (int ks = 0; ks < 2; ++ks) {
                half8 ah[4], bh[4];
#pragma unroll
                for (int mi = 0; mi < 4; ++mi)
                    ah[mi] = *(const half8*)&Ah[aoff[mi][ks]];
#pragma unroll
                for (int ni = 0; ni < 4; ++ni)
                    bh[ni] = *(const half8*)&Bh[boff[ni][ks]];
#pragma unroll
                for (int mi = 0; mi < 4; ++mi)
#pragma unroll
                    for (int ni = 0; ni < 4; ++ni)
                        acc[mi][ni] = MFMA16F(ah[mi], bh[ni], acc[mi][ni]);
            }
            __builtin_amdgcn_s_setprio(0);
            __syncthreads();
        }
    }

    const int hh = n >> 2, nl = n & 3;
    const int pxbase = p0 + (w & 1) * 64 + lq * 4;
    const int x0q = pxbase & 7;
#pragma unroll
    for (int mi = 0; mi < 4; ++mi) {
        int px = pxbase + mi * 16;
        int y = px >> 3;
#pragma unroll
        for (int ni = 0; ni < 4; ++ni) {
            int co = co0 + (w >> 1) * 64 + ni * 16 + lm;
            int nn = nl * 8 + (co >> 6);
            int dd = (co & 63) * 8 + (y >> 2);
            int t0 = hh * 32 + (y & 3) * 8 + x0q;
            if (z < 2) {                       // Q,K: single f16
                unsigned short* O = (z == 0) ? Qh : Kh;
                short4v hv;
#pragma unroll
                for (int r = 0; r < 4; ++r) hv[r] = (short)f2h(acc[mi][ni][r]);
                *(short4v*)&O[(nn * 512 + dd) * 256 + t0] = hv;
            } else {                           // V: f16 transposed
#pragma unroll
                for (int r = 0; r < 4; ++r)
                    Vt[(nn * 256 + t0 + r) * 512 + dd] = f2h(acc[mi][ni][r]);
            }
        }
    }
}

// ---- FUSED scores+softmax: 64q x 512k/block, 512 thr, grid (8,32) ----
__global__ __launch_bounds__(512) void k_scores_sm(
        const unsigned short* __restrict__ Qh, const unsigned short* __restrict__ Kh,
        float* __restrict__ Sc, unsigned short* __restrict__ Ph,
        uint4* __restrict__ Spz) {
    __shared__ __align__(16) short Ah[4096], Bh[32768];  // 8KB + 64KB
    __shared__ float Mw[8][64], Sw[8][64];               // 4KB
    const int tid = threadIdx.x;
    const int nn = blockIdx.y, q0 = blockIdx.x * 64;

    // zero Sp (660480 uint4 over 131072 threads)
    {
        unsigned g = (blockIdx.y * 8u + blockIdx.x) * 512u + tid;
#pragma unroll
        for (int i = 0; i < 6; ++i) {
            unsigned zi = g + (unsigned)i * 131072u;
            if (zi < 660480u) Spz[zi] = (uint4){0u, 0u, 0u, 0u};
        }
    }

    const int w = tid >> 6, l = tid & 63;
    const int wq = w & 1, wk = w >> 1;
    const int lm = l & 15, lq = l >> 4;

    // staging addresses (pitch-64 swizzle on global src; LDS dest linear)
    const int ar = tid >> 3, ac = (tid & 7) ^ ((tid >> 3) & 7);   // A: 64 rows
    const int arow = (nn * 512 + q0 + ar) * 256 + ac * 8;
    int brow[8];
#pragma unroll
    for (int it = 0; it < 8; ++it) {
        int u = it * 512 + tid;
        int row = u >> 3, slot = u & 7;
        brow[it] = (nn * 512 + row) * 256 + ((slot ^ (row & 7)) * 8);
    }

    int aoff[2][2], boff[8][2];
#pragma unroll
    for (int mi = 0; mi < 2; ++mi) {
        int row = wq * 32 + mi * 16 + lm;
#pragma unroll
        for (int ks = 0; ks < 2; ++ks)
            aoff[mi][ks] = row * 64 + ((((ks << 2) | lq) ^ (row & 7)) * 8);
    }
#pragma unroll
    for (int ni = 0; ni < 8; ++ni) {
        int row = wk * 128 + ni * 16 + lm;
#pragma unroll
        for (int ks = 0; ks < 2; ++ks)
            boff[ni][ks] = row * 64 + ((((ks << 2) | lq) ^ (row & 7)) * 8);
    }

    f32x4 acc[2][8];
#pragma unroll
    for (int mi = 0; mi < 2; ++mi)
#pragma unroll
        for (int ni = 0; ni < 8; ++ni) acc[mi][ni] = (f32x4){0.f, 0.f, 0.f, 0.f};

    for (int tc = 0; tc < 256; tc += 64) {
        gl_lds16(Qh + arow + tc, (char*)Ah + tid * 16);
#pragma unroll
        for (int it = 0; it < 8; ++it)
            gl_lds16(Kh + brow[it] + tc, (char*)Bh + (it * 512 + tid) * 16);
        __syncthreads();
        __builtin_amdgcn_s_setprio(1);
#pragma unroll
        for (int ks = 0; ks < 2; ++ks) {
            half8 ah[2], bh[8];
#pragma unroll
            for (int mi = 0; mi < 2; ++mi) ah[mi] = *(const half8*)&Ah[aoff[mi][ks]];
#pragma unroll
            for (int ni = 0; ni < 8; ++ni) bh[ni] = *(const half8*)&Bh[boff[ni][ks]];
#pragma unroll
            for (int mi = 0; mi < 2; ++mi)
#pragma unroll
                for (int ni = 0; ni < 8; ++ni)
                    acc[mi][ni] = MFMA16F(ah[mi], bh[ni], acc[mi][ni]);
        }
        __builtin_amdgcn_s_setprio(0);
        __syncthreads();
    }

    // ---- in-register softmax over k ----
    float M[2][4];
#pragma unroll
    for (int mi = 0; mi < 2; ++mi)
#pragma unroll
        for (int r = 0; r < 4; ++r) {
            float m = acc[mi][0][r];
#pragma unroll
            for (int ni = 1; ni < 8; ++ni) m = fmaxf(m, acc[mi][ni][r]);
#pragma unroll
            for (int off = 1; off < 16; off <<= 1) m = fmaxf(m, __shfl_xor(m, off));
            M[mi][r] = m;
            if (lm == 0) Mw[w][wq * 32 + mi * 16 + lq * 4 + r] = m;
        }
    __syncthreads();
#pragma unroll
    for (int mi = 0; mi < 2; ++mi)
#pragma unroll
        for (int r = 0; r < 4; ++r) {
            int q_l = wq * 32 + mi * 16 + lq * 4 + r;
            float m = fmaxf(fmaxf(Mw[wq][q_l], Mw[wq + 2][q_l]),
                            fmaxf(Mw[wq + 4][q_l], Mw[wq + 6][q_l]));
            M[mi][r] = m;
        }
#pragma unroll
    for (int mi = 0; mi < 2; ++mi)
#pragma unroll
        for (int r = 0; r < 4; ++r) {
            float m = M[mi][r];
            float s = 0.f;
#pragma unroll
            for (int ni = 0; ni < 8; ++ni) {
                float e = __expf(acc[mi][ni][r] - m);
                acc[mi][ni][r] = e;
                s += e;
            }
#pragma unroll
            for (int off = 1; off < 16; off <<= 1) s += __shfl_xor(s, off);
            if (lm == 0) Sw[w][wq * 32 + mi * 16 + lq * 4 + r] = s;
        }
    __syncthreads();
    float* C = Sc + nn * 262144;
    unsigned short* P = Ph + nn * 262144;
#pragma unroll
    for (int mi = 0; mi < 2; ++mi)
#pragma unroll
        for (int r = 0; r < 4; ++r) {
            int q_l = wq * 32 + mi * 16 + lq * 4 + r;
            float s = ((Sw[wq][q_l] + Sw[wq + 2][q_l]) +
                       (Sw[wq + 4][q_l] + Sw[wq + 6][q_l]));
            float inv = 1.0f / s;
            int rowbase = (q0 + q_l) * 512 + wk * 128 + lm;
#pragma unroll
            for (int ni = 0; ni < 8; ++ni) {
                float p = acc[mi][ni][r] * inv;
                C[rowbase + ni * 16] = p;
                P[rowbase + ni * 16] = f2h(p);
            }
        }
}

// ---- PV (r13): P @ V, 16x16 f16 MFMA, BK=128, 256 thr, grid (4,4,32) ----
__global__ __launch_bounds__(256) void k_pv_mfma(
        const unsigned short* __restrict__ Ph, const unsigned short* __restrict__ Vt,
        unsigned short* __restrict__ Sp) {
    __shared__ __align__(16) short Ah[16384], Bh[8192];  // [128][128], [64][128]
    const int tid = threadIdx.x;
    const int w = tid >> 6, l = tid & 63;
    const int q0 = blockIdx.x * 128, t0 = blockIdx.y * 64, nn = blockIdx.z;
    const int lm = l & 15, lq = l >> 4;
    const int r4 = l >> 4, c16 = l & 15;                 // pitch-128 stage map

    int arow[8], brow[4];
#pragma unroll
    for (int j = 0; j < 8; ++j) {
        int rt = w * 32 + j * 4 + r4;
        arow[j] = (nn * 512 + q0 + rt) * 512 + ((c16 ^ (rt & 15)) * 8);
    }
#pragma unroll
    for (int j = 0; j < 4; ++j) {
        int rt = w * 16 + j * 4 + r4;
        brow[j] = (nn * 256 + t0 + rt) * 512 + ((c16 ^ (rt & 15)) * 8);
    }
    const int ldsA = w * 8192, ldsB = w * 4096;          // bytes

    int aoff[4][4], boff[2][4];
#pragma unroll
    for (int mi = 0; mi < 4; ++mi) {
        int row = (w & 1) * 64 + mi * 16 + lm;
#pragma unroll
        for (int ks = 0; ks < 4; ++ks)
            aoff[mi][ks] = row * 128 + ((((ks << 2) | lq) ^ (row & 15)) * 8);
    }
#pragma unroll
    for (int ni = 0; ni < 2; ++ni) {
        int row = (w >> 1) * 32 + ni * 16 + lm;
#pragma unroll
        for (int ks = 0; ks < 4; ++ks)
            boff[ni][ks] = row * 128 + ((((ks << 2) | lq) ^ (row & 15)) * 8);
    }

    f32x4 acc[4][2];
#pragma unroll
    for (int mi = 0; mi < 4; ++mi)
#pragma unroll
        for (int ni = 0; ni < 2; ++ni) acc[mi][ni] = (f32x4){0.f, 0.f, 0.f, 0.f};

    for (int kc = 0; kc < 512; kc += 128) {
#pragma unroll
        for (int j = 0; j < 8; ++j)
            gl_lds16(Ph + arow[j] + kc, (char*)Ah + ldsA + j * 1024);
#pragma unroll
        for (int j = 0; j < 4; ++j)
            gl_lds16(Vt + brow[j] + kc, (char*)Bh + ldsB + j * 1024);
        __syncthreads();
#pragma unroll
        for (int ks = 0; ks < 4; ++ks) {
            half8 a[4], b[2];
#pragma unroll
            for (int mi = 0; mi < 4; ++mi) a[mi] = *(const half8*)&Ah[aoff[mi][ks]];
#pragma unroll
            for (int ni = 0; ni < 2; ++ni) b[ni] = *(const half8*)&Bh[boff[ni][ks]];
#pragma unroll
            for (int mi = 0; mi < 4; ++mi)
#pragma unroll
                for (int ni = 0; ni < 2; ++ni)
                    acc[mi][ni] = MFMA16F(a[mi], b[ni], acc[mi][ni]);
        }
        __syncthreads();
    }

    // scatter into Sp[b2][yy][xx][d2]:  b2=nn>>3, s2=nn&7,
    //   ww=(qp>>4)*8+((qp>>1)&7), d2=(qp&1)*256+(t&31)*8+(t>>5)
    const int b2 = nn >> 3, s2 = nn & 7;
#pragma unroll
    for (int mi = 0; mi < 4; ++mi) {
        int qb = q0 + (w & 1) * 64 + lq * 4 + mi * 16;
#pragma unroll
        for (int ni = 0; ni < 2; ++ni) {
            int tc = t0 + (w >> 1) * 32 + ni * 16 + lm;
            int d2base = (tc & 31) * 8 + (tc >> 5);
#pragma unroll
            for (int r = 0; r < 4; ++r) {
                int qp = qb + r;
                int ww = (qp >> 4) * 8 + ((qp >> 1) & 7);
                int d2 = (qp & 1) * 256 + d2base;
                Sp[((b2 * 10 + s2 + 1) * 258 + ww + 1) * 512 + d2] =
                    f2h(acc[mi][ni][r]);
            }
        }
    }
}

// ---- output conv (r13): BM=128 BN=64, BK=128, 256 thr, grid (64,8) ----
__global__ __launch_bounds__(256) void k_conv_o_mfma(
        const unsigned short* __restrict__ Sp, const unsigned short* __restrict__ Wh,
        const float* __restrict__ bias, float* __restrict__ Y) {
    __shared__ __align__(16) short Ah[16384], Bh[8192];  // [128][128], [64][128]
    const int tid = threadIdx.x;
    const int w = tid >> 6, l = tid & 63;
    const int n   = blockIdx.x >> 4;
    const int yy  = (blockIdx.x >> 1) & 7;
    const int x0  = (blockIdx.x & 1) * 128;
    const int co0 = blockIdx.y * 64;
    const int lm = l & 15, lq = l >> 4;
    const int r4 = l >> 4, c16 = l & 15;                 // pitch-128 stage map

    int arow[8], brow[4];
#pragma unroll
    for (int j = 0; j < 8; ++j) {
        int rt = w * 32 + j * 4 + r4;
        arow[j] = ((n * 10 + yy + 1) * 258 + (x0 + rt + 1)) * 512
                  + ((c16 ^ (rt & 15)) * 8);
    }
#pragma unroll
    for (int j = 0; j < 4; ++j) {
        int rt = w * 16 + j * 4 + r4;
        brow[j] = (co0 + rt) * 4608 + ((c16 ^ (rt & 15)) * 8);
    }
    const int ldsA = w * 8192, ldsB = w * 4096;          // bytes

    int aoff[4][4], boff[2][4];
#pragma unroll
    for (int mi = 0; mi < 4; ++mi) {
        int row = (w & 1) * 64 + mi * 16 + lm;
#pragma unroll
        for (int ks = 0; ks < 4; ++ks)
            aoff[mi][ks] = row * 128 + ((((ks << 2) | lq) ^ (row & 15)) * 8);
    }
#pragma unroll
    for (int ni = 0; ni < 2; ++ni) {
        int row = (w >> 1) * 32 + ni * 16 + lm;
#pragma unroll
        for (int ks = 0; ks < 4; ++ks)
            boff[ni][ks] = row * 128 + ((((ks << 2) | lq) ^ (row & 15)) * 8);
    }

    f32x4 acc[4][2];
#pragma unroll
    for (int ni = 0; ni < 2; ++ni) {
        float b = bias[co0 + (w >> 1) * 32 + ni * 16 + lm];
#pragma unroll
        for (int mi = 0; mi < 4; ++mi) acc[mi][ni] = (f32x4){b, b, b, b};
    }

    for (int tap = 0; tap < 9; ++tap) {
        const int tapoff = ((tap / 3 - 1) * 258 + (tap % 3 - 1)) * 512;
        const int wb = tap * 512;
        for (int ci0 = 0; ci0 < 512; ci0 += 128) {
#pragma unroll
            for (int j = 0; j < 8; ++j)
                gl_lds16(Sp + arow[j] + tapoff + ci0, (char*)Ah + ldsA + j * 1024);
#pragma unroll
            for (int j = 0; j < 4; ++j)
                gl_lds16(Wh + brow[j] + wb + ci0, (char*)Bh + ldsB + j * 1024);
            __syncthreads();
#pragma unroll
            for (int ks = 0; ks < 4; ++ks) {
                half8 a[4], b[2];
#pragma unroll
                for (int mi = 0; mi < 4; ++mi)
                    a[mi] = *(const half8*)&Ah[aoff[mi][ks]];
#pragma unroll
                for (int ni = 0; ni < 2; ++ni)
                    b[ni] = *(const half8*)&Bh[boff[ni][ks]];
#pragma unroll
                for (int mi = 0; mi < 4; ++mi)
#pragma unroll
                    for (int ni = 0; ni < 2; ++ni)
                        acc[mi][ni] = MFMA16F(a[mi], b[ni], acc[mi][ni]);
            }
            __syncthreads();
        }
    }

#pragma unroll
    for (int mi = 0; mi < 4; ++mi) {
        int px = x0 + (w & 1) * 64 + lq * 4 + mi * 16;
#pragma unroll
        for (int ni = 0; ni < 2; ++ni) {
            int co = co0 + (w >> 1) * 32 + ni * 16 + lm;
            *(f32x4*)&Y[n * 1048576 + co * 2048 + yy * 256 + px] = acc[mi][ni];
        }
    }
}

// ---------------------------------------------------------------------------
extern "C" void kernel_launch(void* const* d_in, const int* in_sizes, int n_in,
                              void* d_out, int out_size, void* d_ws, size_t ws_size,
                              hipStream_t stream) {
    const float* q  = (const float*)d_in[0];
    const float* k  = (const float*)d_in[1];
    const float* v  = (const float*)d_in[2];
    const float* Wq = (const float*)d_in[3];
    const float* bq = (const float*)d_in[4];
    const float* Wk = (const float*)d_in[5];
    const float* bk = (const float*)d_in[6];
    const float* Wv = (const float*)d_in[7];
    const float* bv = (const float*)d_in[8];
    const float* Wo = (const float*)d_in[9];
    const float* bo = (const float*)d_in[10];

    // ---- workspace layout (shorts) ----
    unsigned short* W0  = (unsigned short*)d_ws;
    unsigned short* Wqh = W0;                   // 2359296
    unsigned short* Wkh = W0 + 2359296;         // 2359296
    unsigned short* Wvh = W0 + 4718592;         // 2359296
    unsigned short* Xvh = W0 + 7077888;         // 5570560 (ends 12648448)
    unsigned short* Sp  = W0 + 12648448;        // 5283840 (no overlap with Ph@0,
                                                //  Woh@18219008, Qh/Kh/Vt)
    unsigned short* Woh = W0 + 18219008;        // 2359296 (alive till conv_o)
    unsigned short* Qh  = W0 + 20578304;        // 4194304
    unsigned short* Kh  = W0 + 28966912;        // 4194304
    unsigned short* Vt  = W0 + 33161216;        // 4194304 (alive till pv)
    // reuses: Ph @0 (8388608, over Wqh/Wkh/Wvh/Xvh-head — dead after conv)
    unsigned short* Ph = W0;                    // 8388608 shorts

    // ---- d_out scratch before final writes ----
    float* y_out = (float*)d_out;               // 4194304 floats (written last)
    float* attn  = y_out + 4194304;             // 8388608 floats (by scores_sm)
    unsigned short* Xqh = (unsigned short*)d_out;
    unsigned short* Xkh = (unsigned short*)attn;

    k_prep_fused<<<5600, 256, 0, stream>>>(q, k, v, Wq, Wk, Wv, Wo,
                                           Wqh, Wkh, Wvh, Woh,
                                           Xqh, Xkh, Xvh);
    k_conv_qkv_all<<<dim3(64, 4, 3), 256, 0, stream>>>(
        Xqh, Xkh, Xvh, Wqh, Wkh, Wvh,
        bq, bk, bv, Qh, Kh, Vt);
    k_scores_sm<<<dim3(8, 32), 512, 0, stream>>>(Qh, Kh, attn, Ph, (uint4*)Sp);
    k_pv_mfma<<<dim3(4, 4, 32), 256, 0, stream>>>(Ph, Vt, Sp);
    k_conv_o_mfma<<<dim3(64, 8), 256, 0, stream>>>(Sp, Woh, bo, y_out);
}